// Round 10
// baseline (1882.944 us; speedup 1.0000x reference)
//
#include <hip/hip_runtime.h>

#define NB 4
#define NN 16384
#define NPT 1024
#define NS 32
#define CIN 64
#define C0 67

typedef float v2f __attribute__((ext_vector_type(2)));

// DPP wave64 reduce ladders (VALU-only; HW-verified correct in rounds 3/5/6/9 passing runs)
#define DPP_MAXF(r, ctrl)                                                                   \
  {                                                                                         \
    unsigned _m = (unsigned)__builtin_amdgcn_update_dpp(                                    \
        (int)__float_as_uint(r), (int)__float_as_uint(r), ctrl, 0xf, 0xf, false);           \
    r = fmaxf(r, __uint_as_float(_m));                                                      \
  }
#define DPP_MINU(r, ctrl)                                                                   \
  {                                                                                         \
    unsigned _m = (unsigned)__builtin_amdgcn_update_dpp((int)(r), (int)(r), ctrl, 0xf, 0xf, \
                                                        false);                             \
    r = (r < _m) ? r : _m;                                                                  \
  }

// ---------------- FPS: one block per batch, 512 threads, 32 pts/thread ----------------
// Round-9 proven core (1552us). This round's only change: the per-iteration tid0 GLOBAL
// store of the centroid is replaced by an LDS accumulator + one coalesced copy at the end.
// Rationale: __syncthreads drains vmcnt(0) -- the global store's completion sat on the
// serial chain every iteration; a ds_write drains in ~20-40cyc instead. Everything else
// (scan, post-scan argmax, DPP ladders, u64 ~j key merge) is byte-identical to round 9.
extern "C" __global__ __attribute__((amdgpu_waves_per_eu(2, 2))) __launch_bounds__(512)
void fps_kernel(const float* __restrict__ xyz, float* __restrict__ newxyz) {
  const int b = blockIdx.x;
  const int tid = threadIdx.x;          // 0..511
  const int wv = tid >> 6, lane = tid & 63;
  const float* base = xyz + (size_t)b * (NN * 3);
  __shared__ unsigned long long part[2][8];  // parity-double-buffered wave-winner keys
  __shared__ float sonew[NPT * 3];           // centroid accumulator (12 KB)
  v2f x2[16], y2[16], z2[16], m2[16];
#pragma unroll
  for (int k = 0; k < 32; ++k) {
    int j = (k << 9) + tid;            // same global index mapping as rounds 0-9
    x2[k >> 1][k & 1] = base[3 * j + 0];
    y2[k >> 1][k & 1] = base[3 * j + 1];
    z2[k >> 1][k & 1] = base[3 * j + 2];
    m2[k >> 1][k & 1] = 1e10f;
  }
  // iteration 0: centroid = point 0 (broadcast load)
  float cx = base[0], cy = base[1], cz = base[2];
  if (tid == 0) { sonew[0] = cx; sonew[1] = cy; sonew[2] = cz; }
  v2f cx2 = {cx, cx}, cy2 = {cy, cy}, cz2 = {cz, cz};
  for (int it = 1; it < NPT; ++it) {
    const int p = it & 1;
    float bv = -1.0f;
    {
#pragma clang fp contract(off)
#pragma unroll
      for (int q = 0; q < 16; ++q) {
        v2f dx = x2[q] - cx2;          // exact IEEE sub per half
        v2f dy = y2[q] - cy2;
        v2f dz = z2[q] - cz2;
        v2f qx = dx * dx;              // no contraction (pragma)
        v2f qy = dy * dy;
        v2f qz = dz * dz;
        v2f ss = qx + qy;              // (dx2+dy2)
        v2f dd = ss + qz;              // +dz2   -- reference's exact order
        float a = fminf(m2[q].x, dd.x);
        float bmn = fminf(m2[q].y, dd.y);
        m2[q].x = a;
        m2[q].y = bmn;
        bv = fmaxf(bv, fmaxf(a, bmn)); // fuses to v_max3_f32
      }
    }
    // post-scan: smallest k with md[k]==bv (descending overwrite keeps smallest)
    int bk = 0;
#pragma unroll
    for (int k = 31; k >= 0; --k) {
      float v = (k & 1) ? m2[k >> 1].y : m2[k >> 1].x;
      bk = (v == bv) ? k : bk;
    }
    int bestj = (bk << 9) + tid;
    // phase A: wave max of bv via DPP ladder -> lane 63
    float r = bv;
    DPP_MAXF(r, 0x111); DPP_MAXF(r, 0x112); DPP_MAXF(r, 0x114);
    DPP_MAXF(r, 0x118); DPP_MAXF(r, 0x142); DPP_MAXF(r, 0x143);
    float wmax = __uint_as_float((unsigned)__builtin_amdgcn_readlane((int)__float_as_uint(r), 63));
    // phase B: min index among lanes holding the max (exact equality: min/max return operands)
    unsigned cj = (bv == wmax) ? (unsigned)bestj : 0x7FFFFFFFu;
    DPP_MINU(cj, 0x111); DPP_MINU(cj, 0x112); DPP_MINU(cj, 0x114);
    DPP_MINU(cj, 0x118); DPP_MINU(cj, 0x142); DPP_MINU(cj, 0x143);
    unsigned jw = (unsigned)__builtin_amdgcn_readlane((int)cj, 63);
    if (lane == 0)
      part[p][wv] = ((unsigned long long)__float_as_uint(wmax) << 32) | (unsigned)(~jw);
    __syncthreads();
    // every thread merges the 8 wave winners (broadcast LDS reads); ~j orders ties to min j
    unsigned long long g = part[p][0];
#pragma unroll
    for (int w = 1; w < 8; ++w) {
      unsigned long long o = part[p][w];
      g = (o > g) ? o : g;
    }
    int j = (int)(~(unsigned)g);
    int js = __builtin_amdgcn_readfirstlane(j);      // uniform -> scalar loads
    const float* pc = base + 3 * js;
    cx = pc[0]; cy = pc[1]; cz = pc[2];              // bit-identical to source coords
    if (tid == 0) { float* o3 = sonew + 3 * it; o3[0] = cx; o3[1] = cy; o3[2] = cz; }
    cx2.x = cx; cx2.y = cx;
    cy2.x = cy; cy2.y = cy;
    cz2.x = cz; cz2.y = cz;
    // no second barrier: next iteration writes the OTHER parity's part[] cells
  }
  __syncthreads();
  // one coalesced copy of all 1024 centroids (3072 floats) to global
  float* onew = newxyz + (size_t)b * (NPT * 3);
  for (int i = tid; i < NPT * 3; i += 512) onew[i] = sonew[i];
}

// ---------------- Feature transpose: (B,C,N) -> (B,N,C), 64x64 LDS tiles ----------------
// mlp's gather reads feats[cc*NN + j] at scattered j: 64 lanes x 64 distinct 64B lines,
// 4B used each => ~16x line-waste on the L2/L3 path. One 16.8MB point-major copy makes
// each sample's 64 channels one contiguous 256B read. Bit-preserving (pure copy).
extern "C" __global__ __launch_bounds__(256)
void tr_kernel(const float* __restrict__ feats, float* __restrict__ featsT) {
  const int tile = blockIdx.x & 255;    // NN/64 = 256 tiles
  const int b = blockIdx.x >> 8;
  const int j0 = tile * 64;
  __shared__ float t[64][65];           // +1 pad: conflict-free both phases
  const int lj = threadIdx.x & 63;      // lane = j (read) / cc (write)
  const int r0 = threadIdx.x >> 6;      // 0..3
  const float* fb = feats + (size_t)b * (CIN * NN);
#pragma unroll
  for (int cc = r0; cc < 64; cc += 4)
    t[cc][lj] = fb[(size_t)cc * NN + j0 + lj];        // coalesced along j
  __syncthreads();
  float* ob = featsT + (size_t)b * (NN * CIN);
#pragma unroll
  for (int jr = r0; jr < 64; jr += 4)
    ob[(size_t)(j0 + jr) * 64 + lj] = t[lj][jr];      // coalesced along cc
}

// ---- Fused ball query + gather + MLP(67->64->64->128) + max-pool, one block per (b,m) ----
// Ball query folded into wave 0 of each mlp block (verbatim round-9 ball logic, output to
// LDS sidx instead of global ballidx): removes one kernel launch and the ballidx global
// round-trip; the ~3us/block scan hides under 8-blocks/CU overlap.
extern "C" __global__ __launch_bounds__(256)
void mlp_kernel(const float* __restrict__ xyz, const float* __restrict__ feats,
                const float* __restrict__ featsT,   // point-major copy, or null (fallback)
                const float* __restrict__ newxyz,
                const float* __restrict__ W1, const float* __restrict__ b1,
                const float* __restrict__ W2, const float* __restrict__ b2,
                const float* __restrict__ W3, const float* __restrict__ b3,
                float* __restrict__ outf) {
  const int bm = blockIdx.x;
  const int b = bm >> 10, m = bm & 1023;
  const int tid = threadIdx.x;
  __align__(16) __shared__ float bufA[32 * 68];  // h0 (stride 68), then h2 (stride 64)
  __align__(16) __shared__ float bufB[32 * 64];  // h1, then partial max
  __shared__ int blist[NS];
  __shared__ int sidx[NS];
  const float* cb = newxyz + (size_t)bm * 3;
  float cx = cb[0], cy = cb[1], cz = cb[2];
  // ---- ball query on wave 0 (identical semantics to the round-9 ball_kernel) ----
  if (tid < 64) {
    const int lane = tid;
    const float* base = xyz + (size_t)b * (NN * 3);
    float c2 = __fadd_rn(__fadd_rn(__fmul_rn(cx, cx), __fmul_rn(cy, cy)), __fmul_rn(cz, cz));
    int cnt = 0;
    for (int j0 = 0; j0 < NN; j0 += 64) {
      int j = j0 + lane;
      float xx = base[3 * j + 0], xy = base[3 * j + 1], xz = base[3 * j + 2];
      float x2 = __fadd_rn(__fadd_rn(__fmul_rn(xx, xx), __fmul_rn(xy, xy)), __fmul_rn(xz, xz));
      float dt = __fadd_rn(__fadd_rn(__fmul_rn(cx, xx), __fmul_rn(cy, xy)), __fmul_rn(cz, xz));
      float d2 = __fsub_rn(__fadd_rn(c2, x2), __fmul_rn(2.0f, dt));  // (c2+x2) - 2*dot
      bool in = d2 < 0.25f;
      unsigned long long msk = __ballot(in);
      if (in) {
        int pos = cnt + (int)__popcll(msk & ((1ull << lane) - 1ull));
        if (pos < NS) blist[pos] = j;
      }
      cnt += (int)__popcll(msk);
      if (cnt >= NS) break;
    }
    if (lane < NS) {
      int v;
      if (cnt == 0) v = 0;
      else v = (lane < cnt) ? blist[lane] : blist[0];
      sidx[lane] = v;
    }
  }
  __syncthreads();
  // gather: 8 threads per sample
  {
    int s = tid >> 3, q = tid & 7;
    int j = sidx[s];
    float* row = bufA + s * 68;
    if (featsT) {
      const float* fr = featsT + ((size_t)b * NN + j) * 64 + (q << 3);
      float4 a0 = *(const float4*)fr;
      float4 a1 = *(const float4*)(fr + 4);
      float* rp = row + 3 + (q << 3);
      rp[0] = a0.x; rp[1] = a0.y; rp[2] = a0.z; rp[3] = a0.w;
      rp[4] = a1.x; rp[5] = a1.y; rp[6] = a1.z; rp[7] = a1.w;
    } else {
      const float* fb = feats + (size_t)b * (CIN * NN) + j;
#pragma unroll
      for (int u = 0; u < 8; ++u) {
        int cc = (q << 3) + u;
        row[3 + cc] = fb[(size_t)cc * NN];
      }
    }
    if (q == 0) {
      const float* p = xyz + ((size_t)b * NN + j) * 3;
      row[0] = __fsub_rn(p[0], cx);
      row[1] = __fsub_rn(p[1], cy);
      row[2] = __fsub_rn(p[2], cz);
      row[67] = 0.0f;
    }
  }
  __syncthreads();
  // layer 1: 67->64   (thread = (o, 8-sample group))
  {
    const int o = tid & 63, g = tid >> 6;
    float w[68];
    const float* wr = W1 + o * C0;
#pragma unroll
    for (int c = 0; c < C0; ++c) w[c] = wr[c];
    w[67] = 0.0f;
    float bias = b1[o];
    float acc[8];
#pragma unroll
    for (int k = 0; k < 8; ++k) acc[k] = bias;
#pragma unroll
    for (int c = 0; c < 68; c += 4) {
#pragma unroll
      for (int k = 0; k < 8; ++k) {
        float4 h = *(const float4*)(bufA + (g * 8 + k) * 68 + c);
        acc[k] = fmaf(w[c], h.x, acc[k]);
        acc[k] = fmaf(w[c + 1], h.y, acc[k]);
        acc[k] = fmaf(w[c + 2], h.z, acc[k]);
        acc[k] = fmaf(w[c + 3], h.w, acc[k]);
      }
    }
#pragma unroll
    for (int k = 0; k < 8; ++k) bufB[(g * 8 + k) * 64 + o] = fmaxf(acc[k], 0.0f);
  }
  __syncthreads();
  // layer 2: 64->64, h2 into bufA with stride 64
  {
    const int o = tid & 63, g = tid >> 6;
    float w[64];
    const float* wr = W2 + o * 64;
#pragma unroll
    for (int c = 0; c < 64; ++c) w[c] = wr[c];
    float bias = b2[o];
    float acc[8];
#pragma unroll
    for (int k = 0; k < 8; ++k) acc[k] = bias;
#pragma unroll
    for (int c = 0; c < 64; c += 4) {
#pragma unroll
      for (int k = 0; k < 8; ++k) {
        float4 h = *(const float4*)(bufB + (g * 8 + k) * 64 + c);
        acc[k] = fmaf(w[c], h.x, acc[k]);
        acc[k] = fmaf(w[c + 1], h.y, acc[k]);
        acc[k] = fmaf(w[c + 2], h.z, acc[k]);
        acc[k] = fmaf(w[c + 3], h.w, acc[k]);
      }
    }
#pragma unroll
    for (int k = 0; k < 8; ++k) bufA[(g * 8 + k) * 64 + o] = fmaxf(acc[k], 0.0f);
  }
  __syncthreads();
  // layer 3: 64->128 (thread = (o128, 16-sample group)), fused relu+max
  {
    const int o = tid & 127, g = tid >> 7;
    float w[64];
    const float* wr = W3 + o * 64;
#pragma unroll
    for (int c = 0; c < 64; ++c) w[c] = wr[c];
    float bias = b3[o];
    float acc[16];
#pragma unroll
    for (int k = 0; k < 16; ++k) acc[k] = bias;
#pragma unroll
    for (int kb = 0; kb < 16; kb += 8) {   // 8-sample sub-blocks to limit live registers
#pragma unroll
      for (int c = 0; c < 64; c += 4) {
#pragma unroll
        for (int k = 0; k < 8; ++k) {
          float4 h = *(const float4*)(bufA + (g * 16 + kb + k) * 64 + c);
          acc[kb + k] = fmaf(w[c], h.x, acc[kb + k]);
          acc[kb + k] = fmaf(w[c + 1], h.y, acc[kb + k]);
          acc[kb + k] = fmaf(w[c + 2], h.z, acc[kb + k]);
          acc[kb + k] = fmaf(w[c + 3], h.w, acc[kb + k]);
        }
      }
    }
    float mx = 0.0f;
#pragma unroll
    for (int k = 0; k < 16; ++k) mx = fmaxf(mx, fmaxf(acc[k], 0.0f));
    bufB[g * 128 + o] = mx;
  }
  __syncthreads();
  if (tid < 128) {
    float v = fmaxf(bufB[tid], bufB[128 + tid]);
    outf[((size_t)b * 128 + tid) * NPT + m] = v;
  }
}

extern "C" void kernel_launch(void* const* d_in, const int* in_sizes, int n_in,
                              void* d_out, int out_size, void* d_ws, size_t ws_size,
                              hipStream_t stream) {
  const float* xyz   = (const float*)d_in[0];
  const float* feats = (const float*)d_in[1];
  const float* W1 = (const float*)d_in[2];
  const float* b1 = (const float*)d_in[3];
  const float* W2 = (const float*)d_in[4];
  const float* b2 = (const float*)d_in[5];
  const float* W3 = (const float*)d_in[6];
  const float* b3 = (const float*)d_in[7];
  float* out = (float*)d_out;
  float* newxyz = out;                 // (4,1024,3)
  float* outf = out + NB * NPT * 3;    // (4,128,1024)

  // featsT (16.78 MB) lives at ws+1MB if the workspace is big enough; else fall back
  const size_t ftOff = 1u << 20;
  const size_t ftBytes = (size_t)NB * NN * CIN * sizeof(float);
  float* featsT = (ws_size >= ftOff + ftBytes) ? (float*)((char*)d_ws + ftOff) : nullptr;

  if (featsT)
    hipLaunchKernelGGL(tr_kernel, dim3(NB * (NN / 64)), dim3(256), 0, stream, feats, featsT);
  hipLaunchKernelGGL(fps_kernel, dim3(NB), dim3(512), 0, stream, xyz, newxyz);
  hipLaunchKernelGGL(mlp_kernel, dim3(NB * NPT), dim3(256), 0, stream,
                     xyz, feats, featsT, newxyz, W1, b1, W2, b2, W3, b3, outf);
}

// Round 11
// 1809.366 us; speedup vs baseline: 1.0407x; 1.0407x over previous
//
#include <hip/hip_runtime.h>

#define NB 4
#define NN 16384
#define NPT 1024
#define NS 32
#define CIN 64
#define C0 67

typedef float v2f __attribute__((ext_vector_type(2)));

// DPP wave64 reduce ladders (VALU-only; HW-verified correct in rounds 3/5/6/9/10 passing runs)
#define DPP_MAXF(r, ctrl)                                                                   \
  {                                                                                         \
    unsigned _m = (unsigned)__builtin_amdgcn_update_dpp(                                    \
        (int)__float_as_uint(r), (int)__float_as_uint(r), ctrl, 0xf, 0xf, false);           \
    r = fmaxf(r, __uint_as_float(_m));                                                      \
  }
#define DPP_MINU(r, ctrl)                                                                   \
  {                                                                                         \
    unsigned _m = (unsigned)__builtin_amdgcn_update_dpp((int)(r), (int)(r), ctrl, 0xf, 0xf, \
                                                        false);                             \
    r = (r < _m) ? r : _m;                                                                  \
  }

// ------- Fused FPS (blocks 0..3) + feature transpose (blocks 4..4+NB*256-1) -------
// Round-10 verdicts: LDS centroid accumulator = WIN (-20us, vmcnt drain off the serial
// chain); ball-into-mlp fusion = REGRESSION (-95us: wave0 scans while waves 1-3 idle at
// the barrier -- standalone ball keeps all 4 SIMDs on independent centroids). This round
// keeps the fps win, reverts the fusion, and hides tr's ~10-15us serial launch inside
// fps's 1532us shadow: one kernel, role-switched on blockIdx.x. Streams are serial under
// graph capture; extra blocks on the 252 idle CUs are the only way to overlap.
// FPS core byte-identical to round 10 (1532us proven): pk-f32 scan (contract off,
// (dx2+dy2)+dz2 order), post-scan argmax (min/max return operands => equality exact),
// DPP ladders, u64 ~j key merge -> ties to smallest global j (numpy argmax semantics).
extern "C" __global__ __attribute__((amdgpu_waves_per_eu(2, 2))) __launch_bounds__(512)
void fps_kernel(const float* __restrict__ xyz, float* __restrict__ newxyz,
                const float* __restrict__ feats, float* __restrict__ featsT) {
  __shared__ unsigned long long part[2][8];  // parity-double-buffered wave-winner keys
  __shared__ float sonew[NPT * 3];           // centroid accumulator (12 KB)
  __shared__ float t[64][65];                // transpose tile (16.6 KB; disjoint role)
  const int tid = threadIdx.x;
  if (blockIdx.x >= NB) {
    // ---------------- transpose role: (B,C,N) -> (B,N,C), 64x64 tile ----------------
    const int tt = blockIdx.x - NB;
    const int tile = tt & 255, b = tt >> 8;
    const int j0 = tile * 64;
    const int lj = tid & 63;            // lane = j (read) / cc (write)
    const int r0 = tid >> 6;            // 0..7
    const float* fb = feats + (size_t)b * (CIN * NN);
#pragma unroll
    for (int cc = r0; cc < 64; cc += 8)
      t[cc][lj] = fb[(size_t)cc * NN + j0 + lj];      // coalesced along j
    __syncthreads();
    float* ob = featsT + (size_t)b * (NN * CIN);
#pragma unroll
    for (int jr = r0; jr < 64; jr += 8)
      ob[(size_t)(j0 + jr) * 64 + lj] = t[lj][jr];    // coalesced along cc
    return;
  }
  // ---------------- FPS role: one block per batch, 512 threads, 32 pts/thread ----------
  const int b = blockIdx.x;
  const int wv = tid >> 6, lane = tid & 63;
  const float* base = xyz + (size_t)b * (NN * 3);
  v2f x2[16], y2[16], z2[16], m2[16];
#pragma unroll
  for (int k = 0; k < 32; ++k) {
    int j = (k << 9) + tid;            // same global index mapping as rounds 0-10
    x2[k >> 1][k & 1] = base[3 * j + 0];
    y2[k >> 1][k & 1] = base[3 * j + 1];
    z2[k >> 1][k & 1] = base[3 * j + 2];
    m2[k >> 1][k & 1] = 1e10f;
  }
  // iteration 0: centroid = point 0 (broadcast load)
  float cx = base[0], cy = base[1], cz = base[2];
  if (tid == 0) { sonew[0] = cx; sonew[1] = cy; sonew[2] = cz; }
  v2f cx2 = {cx, cx}, cy2 = {cy, cy}, cz2 = {cz, cz};
  for (int it = 1; it < NPT; ++it) {
    const int p = it & 1;
    float bv = -1.0f;
    {
#pragma clang fp contract(off)
#pragma unroll
      for (int q = 0; q < 16; ++q) {
        v2f dx = x2[q] - cx2;          // exact IEEE sub per half
        v2f dy = y2[q] - cy2;
        v2f dz = z2[q] - cz2;
        v2f qx = dx * dx;              // no contraction (pragma)
        v2f qy = dy * dy;
        v2f qz = dz * dz;
        v2f ss = qx + qy;              // (dx2+dy2)
        v2f dd = ss + qz;              // +dz2   -- reference's exact order
        float a = fminf(m2[q].x, dd.x);
        float bmn = fminf(m2[q].y, dd.y);
        m2[q].x = a;
        m2[q].y = bmn;
        bv = fmaxf(bv, fmaxf(a, bmn)); // fuses to v_max3_f32
      }
    }
    // post-scan: smallest k with md[k]==bv (descending overwrite keeps smallest)
    int bk = 0;
#pragma unroll
    for (int k = 31; k >= 0; --k) {
      float v = (k & 1) ? m2[k >> 1].y : m2[k >> 1].x;
      bk = (v == bv) ? k : bk;
    }
    int bestj = (bk << 9) + tid;
    // phase A: wave max of bv via DPP ladder -> lane 63
    float r = bv;
    DPP_MAXF(r, 0x111); DPP_MAXF(r, 0x112); DPP_MAXF(r, 0x114);
    DPP_MAXF(r, 0x118); DPP_MAXF(r, 0x142); DPP_MAXF(r, 0x143);
    float wmax = __uint_as_float((unsigned)__builtin_amdgcn_readlane((int)__float_as_uint(r), 63));
    // phase B: min index among lanes holding the max (exact equality: min/max return operands)
    unsigned cj = (bv == wmax) ? (unsigned)bestj : 0x7FFFFFFFu;
    DPP_MINU(cj, 0x111); DPP_MINU(cj, 0x112); DPP_MINU(cj, 0x114);
    DPP_MINU(cj, 0x118); DPP_MINU(cj, 0x142); DPP_MINU(cj, 0x143);
    unsigned jw = (unsigned)__builtin_amdgcn_readlane((int)cj, 63);
    if (lane == 0)
      part[p][wv] = ((unsigned long long)__float_as_uint(wmax) << 32) | (unsigned)(~jw);
    __syncthreads();
    // every thread merges the 8 wave winners (broadcast LDS reads); ~j orders ties to min j
    unsigned long long g = part[p][0];
#pragma unroll
    for (int w = 1; w < 8; ++w) {
      unsigned long long o = part[p][w];
      g = (o > g) ? o : g;
    }
    int j = (int)(~(unsigned)g);
    int js = __builtin_amdgcn_readfirstlane(j);      // uniform -> scalar loads
    const float* pc = base + 3 * js;
    cx = pc[0]; cy = pc[1]; cz = pc[2];              // bit-identical to source coords
    if (tid == 0) { float* o3 = sonew + 3 * it; o3[0] = cx; o3[1] = cy; o3[2] = cz; }
    cx2.x = cx; cx2.y = cx;
    cy2.x = cy; cy2.y = cy;
    cz2.x = cz; cz2.y = cz;
    // no second barrier: next iteration writes the OTHER parity's part[] cells
  }
  __syncthreads();
  // one coalesced copy of all 1024 centroids (3072 floats) to global
  float* onew = newxyz + (size_t)b * (NPT * 3);
  for (int i = tid; i < NPT * 3; i += 512) onew[i] = sonew[i];
}

// ---------------- Ball query: one wave per centroid, ordered append with early exit ----------------
// Standalone (round-9 proven): 4 waves/block on 4 INDEPENDENT centroids keeps all SIMDs
// busy -- measured 95us better than fusing into mlp (round-10 regression).
extern "C" __global__ __launch_bounds__(256)
void ball_kernel(const float* __restrict__ xyz, const float* __restrict__ newxyz,
                 int* __restrict__ ballidx) {
  const int lwv = threadIdx.x >> 6, lane = threadIdx.x & 63;
  const int wid = blockIdx.x * 4 + lwv;  // centroid id, 0..4095
  const int b = wid >> 10;
  const float* base = xyz + (size_t)b * (NN * 3);
  const float* c = newxyz + (size_t)wid * 3;
  float cx = c[0], cy = c[1], cz = c[2];
  float c2 = __fadd_rn(__fadd_rn(__fmul_rn(cx, cx), __fmul_rn(cy, cy)), __fmul_rn(cz, cz));
  __shared__ int list[4][NS];
  int cnt = 0;
  for (int j0 = 0; j0 < NN; j0 += 64) {
    int j = j0 + lane;
    float xx = base[3 * j + 0], xy = base[3 * j + 1], xz = base[3 * j + 2];
    float x2 = __fadd_rn(__fadd_rn(__fmul_rn(xx, xx), __fmul_rn(xy, xy)), __fmul_rn(xz, xz));
    float dt = __fadd_rn(__fadd_rn(__fmul_rn(cx, xx), __fmul_rn(cy, xy)), __fmul_rn(cz, xz));
    float d2 = __fsub_rn(__fadd_rn(c2, x2), __fmul_rn(2.0f, dt));  // (c2+x2) - 2*dot
    bool in = d2 < 0.25f;
    unsigned long long msk = __ballot(in);
    if (in) {
      int pos = cnt + (int)__popcll(msk & ((1ull << lane) - 1ull));
      if (pos < NS) list[lwv][pos] = j;
    }
    cnt += (int)__popcll(msk);
    if (cnt >= NS) break;
  }
  if (lane < NS) {
    int v;
    if (cnt == 0) v = 0;
    else v = (lane < cnt) ? list[lwv][lane] : list[lwv][0];
    ballidx[wid * NS + lane] = v;
  }
}

// ---------------- Gather + MLP(67->64->64->128) + max-pool, one block per (b,m) ----------------
extern "C" __global__ __launch_bounds__(256)
void mlp_kernel(const float* __restrict__ xyz, const float* __restrict__ feats,
                const float* __restrict__ featsT,   // point-major copy, or null (fallback)
                const float* __restrict__ newxyz, const int* __restrict__ ballidx,
                const float* __restrict__ W1, const float* __restrict__ b1,
                const float* __restrict__ W2, const float* __restrict__ b2,
                const float* __restrict__ W3, const float* __restrict__ b3,
                float* __restrict__ outf) {
  const int bm = blockIdx.x;
  const int b = bm >> 10, m = bm & 1023;
  const int tid = threadIdx.x;
  __align__(16) __shared__ float bufA[32 * 68];  // h0 (stride 68), then h2 (stride 64)
  __align__(16) __shared__ float bufB[32 * 64];  // h1, then partial max
  __shared__ int sidx[NS];
  if (tid < NS) sidx[tid] = ballidx[bm * NS + tid];
  const float* cb = newxyz + (size_t)bm * 3;
  float cx = cb[0], cy = cb[1], cz = cb[2];
  __syncthreads();
  // gather: 8 threads per sample
  {
    int s = tid >> 3, q = tid & 7;
    int j = sidx[s];
    float* row = bufA + s * 68;
    if (featsT) {
      const float* fr = featsT + ((size_t)b * NN + j) * 64 + (q << 3);
      float4 a0 = *(const float4*)fr;
      float4 a1 = *(const float4*)(fr + 4);
      float* rp = row + 3 + (q << 3);
      rp[0] = a0.x; rp[1] = a0.y; rp[2] = a0.z; rp[3] = a0.w;
      rp[4] = a1.x; rp[5] = a1.y; rp[6] = a1.z; rp[7] = a1.w;
    } else {
      const float* fb = feats + (size_t)b * (CIN * NN) + j;
#pragma unroll
      for (int u = 0; u < 8; ++u) {
        int cc = (q << 3) + u;
        row[3 + cc] = fb[(size_t)cc * NN];
      }
    }
    if (q == 0) {
      const float* p = xyz + ((size_t)b * NN + j) * 3;
      row[0] = __fsub_rn(p[0], cx);
      row[1] = __fsub_rn(p[1], cy);
      row[2] = __fsub_rn(p[2], cz);
      row[67] = 0.0f;
    }
  }
  __syncthreads();
  // layer 1: 67->64   (thread = (o, 8-sample group))
  {
    const int o = tid & 63, g = tid >> 6;
    float w[68];
    const float* wr = W1 + o * C0;
#pragma unroll
    for (int c = 0; c < C0; ++c) w[c] = wr[c];
    w[67] = 0.0f;
    float bias = b1[o];
    float acc[8];
#pragma unroll
    for (int k = 0; k < 8; ++k) acc[k] = bias;
#pragma unroll
    for (int c = 0; c < 68; c += 4) {
#pragma unroll
      for (int k = 0; k < 8; ++k) {
        float4 h = *(const float4*)(bufA + (g * 8 + k) * 68 + c);
        acc[k] = fmaf(w[c], h.x, acc[k]);
        acc[k] = fmaf(w[c + 1], h.y, acc[k]);
        acc[k] = fmaf(w[c + 2], h.z, acc[k]);
        acc[k] = fmaf(w[c + 3], h.w, acc[k]);
      }
    }
#pragma unroll
    for (int k = 0; k < 8; ++k) bufB[(g * 8 + k) * 64 + o] = fmaxf(acc[k], 0.0f);
  }
  __syncthreads();
  // layer 2: 64->64, h2 into bufA with stride 64
  {
    const int o = tid & 63, g = tid >> 6;
    float w[64];
    const float* wr = W2 + o * 64;
#pragma unroll
    for (int c = 0; c < 64; ++c) w[c] = wr[c];
    float bias = b2[o];
    float acc[8];
#pragma unroll
    for (int k = 0; k < 8; ++k) acc[k] = bias;
#pragma unroll
    for (int c = 0; c < 64; c += 4) {
#pragma unroll
      for (int k = 0; k < 8; ++k) {
        float4 h = *(const float4*)(bufB + (g * 8 + k) * 64 + c);
        acc[k] = fmaf(w[c], h.x, acc[k]);
        acc[k] = fmaf(w[c + 1], h.y, acc[k]);
        acc[k] = fmaf(w[c + 2], h.z, acc[k]);
        acc[k] = fmaf(w[c + 3], h.w, acc[k]);
      }
    }
#pragma unroll
    for (int k = 0; k < 8; ++k) bufA[(g * 8 + k) * 64 + o] = fmaxf(acc[k], 0.0f);
  }
  __syncthreads();
  // layer 3: 64->128 (thread = (o128, 16-sample group)), fused relu+max
  {
    const int o = tid & 127, g = tid >> 7;
    float w[64];
    const float* wr = W3 + o * 64;
#pragma unroll
    for (int c = 0; c < 64; ++c) w[c] = wr[c];
    float bias = b3[o];
    float acc[16];
#pragma unroll
    for (int k = 0; k < 16; ++k) acc[k] = bias;
#pragma unroll
    for (int kb = 0; kb < 16; kb += 8) {   // 8-sample sub-blocks to limit live registers
#pragma unroll
      for (int c = 0; c < 64; c += 4) {
#pragma unroll
        for (int k = 0; k < 8; ++k) {
          float4 h = *(const float4*)(bufA + (g * 16 + kb + k) * 64 + c);
          acc[kb + k] = fmaf(w[c], h.x, acc[kb + k]);
          acc[kb + k] = fmaf(w[c + 1], h.y, acc[kb + k]);
          acc[kb + k] = fmaf(w[c + 2], h.z, acc[kb + k]);
          acc[kb + k] = fmaf(w[c + 3], h.w, acc[kb + k]);
        }
      }
    }
    float mx = 0.0f;
#pragma unroll
    for (int k = 0; k < 16; ++k) mx = fmaxf(mx, fmaxf(acc[k], 0.0f));
    bufB[g * 128 + o] = mx;
  }
  __syncthreads();
  if (tid < 128) {
    float v = fmaxf(bufB[tid], bufB[128 + tid]);
    outf[((size_t)b * 128 + tid) * NPT + m] = v;
  }
}

extern "C" void kernel_launch(void* const* d_in, const int* in_sizes, int n_in,
                              void* d_out, int out_size, void* d_ws, size_t ws_size,
                              hipStream_t stream) {
  const float* xyz   = (const float*)d_in[0];
  const float* feats = (const float*)d_in[1];
  const float* W1 = (const float*)d_in[2];
  const float* b1 = (const float*)d_in[3];
  const float* W2 = (const float*)d_in[4];
  const float* b2 = (const float*)d_in[5];
  const float* W3 = (const float*)d_in[6];
  const float* b3 = (const float*)d_in[7];
  float* out = (float*)d_out;
  float* newxyz = out;                 // (4,1024,3)
  float* outf = out + NB * NPT * 3;    // (4,128,1024)
  int* ballidx = (int*)d_ws;           // 4096*32 ints at ws+0

  // featsT (16.78 MB) lives at ws+1MB if the workspace is big enough; else fall back
  const size_t ftOff = 1u << 20;
  const size_t ftBytes = (size_t)NB * NN * CIN * sizeof(float);
  float* featsT = (ws_size >= ftOff + ftBytes) ? (float*)((char*)d_ws + ftOff) : nullptr;

  // fps blocks 0..3 + transpose blocks 4..4+1023 in ONE launch (tr hides in fps's shadow)
  const int grid = featsT ? (NB + NB * (NN / 64)) : NB;
  hipLaunchKernelGGL(fps_kernel, dim3(grid), dim3(512), 0, stream, xyz, newxyz, feats, featsT);
  hipLaunchKernelGGL(ball_kernel, dim3(NB * NPT / 4), dim3(256), 0, stream, xyz, newxyz, ballidx);
  hipLaunchKernelGGL(mlp_kernel, dim3(NB * NPT), dim3(256), 0, stream,
                     xyz, feats, featsT, newxyz, ballidx, W1, b1, W2, b2, W3, b3, outf);
}

// Round 12
// 1793.717 us; speedup vs baseline: 1.0497x; 1.0087x over previous
//
#include <hip/hip_runtime.h>

#define NB 4
#define NN 16384
#define NPT 1024
#define NS 32
#define CIN 64
#define C0 67

typedef float v2f __attribute__((ext_vector_type(2)));

// DPP wave64 reduce ladders (VALU-only; HW-verified correct in rounds 3/5/6/9/10/11)
#define DPP_MAXF(r, ctrl)                                                                   \
  {                                                                                         \
    unsigned _m = (unsigned)__builtin_amdgcn_update_dpp(                                    \
        (int)__float_as_uint(r), (int)__float_as_uint(r), ctrl, 0xf, 0xf, false);           \
    r = fmaxf(r, __uint_as_float(_m));                                                      \
  }
#define DPP_MINU(r, ctrl)                                                                   \
  {                                                                                         \
    unsigned _m = (unsigned)__builtin_amdgcn_update_dpp((int)(r), (int)(r), ctrl, 0xf, 0xf, \
                                                        false);                             \
    r = (r < _m) ? r : _m;                                                                  \
  }

// ---------------- FPS: one block per batch, 512 threads, 32 pts/thread ----------------
// Round-10 proven standalone version (1532us), byte-identical. Round-11 lesson: fusing
// tr blocks into THIS dispatch costs +33us (co-residency on the 4 fps CUs + HBM
// contention on the serial chain) -- more than tr's 13us standalone launch. Keep pure.
// Core: pk-f32 scan (contract off, (dx2+dy2)+dz2 order), post-scan argmax (min/max
// return operands => equality exact), DPP ladders, u64 ~j key merge (ties -> smallest
// global j, numpy argmax), LDS centroid accumulator (vmcnt drain off the serial chain).
extern "C" __global__ __attribute__((amdgpu_waves_per_eu(2, 2))) __launch_bounds__(512)
void fps_kernel(const float* __restrict__ xyz, float* __restrict__ newxyz) {
  const int b = blockIdx.x;
  const int tid = threadIdx.x;          // 0..511
  const int wv = tid >> 6, lane = tid & 63;
  const float* base = xyz + (size_t)b * (NN * 3);
  __shared__ unsigned long long part[2][8];  // parity-double-buffered wave-winner keys
  __shared__ float sonew[NPT * 3];           // centroid accumulator (12 KB)
  v2f x2[16], y2[16], z2[16], m2[16];
#pragma unroll
  for (int k = 0; k < 32; ++k) {
    int j = (k << 9) + tid;            // same global index mapping as rounds 0-11
    x2[k >> 1][k & 1] = base[3 * j + 0];
    y2[k >> 1][k & 1] = base[3 * j + 1];
    z2[k >> 1][k & 1] = base[3 * j + 2];
    m2[k >> 1][k & 1] = 1e10f;
  }
  // iteration 0: centroid = point 0 (broadcast load)
  float cx = base[0], cy = base[1], cz = base[2];
  if (tid == 0) { sonew[0] = cx; sonew[1] = cy; sonew[2] = cz; }
  v2f cx2 = {cx, cx}, cy2 = {cy, cy}, cz2 = {cz, cz};
  for (int it = 1; it < NPT; ++it) {
    const int p = it & 1;
    float bv = -1.0f;
    {
#pragma clang fp contract(off)
#pragma unroll
      for (int q = 0; q < 16; ++q) {
        v2f dx = x2[q] - cx2;          // exact IEEE sub per half
        v2f dy = y2[q] - cy2;
        v2f dz = z2[q] - cz2;
        v2f qx = dx * dx;              // no contraction (pragma)
        v2f qy = dy * dy;
        v2f qz = dz * dz;
        v2f ss = qx + qy;              // (dx2+dy2)
        v2f dd = ss + qz;              // +dz2   -- reference's exact order
        float a = fminf(m2[q].x, dd.x);
        float bmn = fminf(m2[q].y, dd.y);
        m2[q].x = a;
        m2[q].y = bmn;
        bv = fmaxf(bv, fmaxf(a, bmn)); // fuses to v_max3_f32
      }
    }
    // post-scan: smallest k with md[k]==bv (descending overwrite keeps smallest)
    int bk = 0;
#pragma unroll
    for (int k = 31; k >= 0; --k) {
      float v = (k & 1) ? m2[k >> 1].y : m2[k >> 1].x;
      bk = (v == bv) ? k : bk;
    }
    int bestj = (bk << 9) + tid;
    // phase A: wave max of bv via DPP ladder -> lane 63
    float r = bv;
    DPP_MAXF(r, 0x111); DPP_MAXF(r, 0x112); DPP_MAXF(r, 0x114);
    DPP_MAXF(r, 0x118); DPP_MAXF(r, 0x142); DPP_MAXF(r, 0x143);
    float wmax = __uint_as_float((unsigned)__builtin_amdgcn_readlane((int)__float_as_uint(r), 63));
    // phase B: min index among lanes holding the max (exact equality: min/max return operands)
    unsigned cj = (bv == wmax) ? (unsigned)bestj : 0x7FFFFFFFu;
    DPP_MINU(cj, 0x111); DPP_MINU(cj, 0x112); DPP_MINU(cj, 0x114);
    DPP_MINU(cj, 0x118); DPP_MINU(cj, 0x142); DPP_MINU(cj, 0x143);
    unsigned jw = (unsigned)__builtin_amdgcn_readlane((int)cj, 63);
    if (lane == 0)
      part[p][wv] = ((unsigned long long)__float_as_uint(wmax) << 32) | (unsigned)(~jw);
    __syncthreads();
    // every thread merges the 8 wave winners (broadcast LDS reads); ~j orders ties to min j
    unsigned long long g = part[p][0];
#pragma unroll
    for (int w = 1; w < 8; ++w) {
      unsigned long long o = part[p][w];
      g = (o > g) ? o : g;
    }
    int j = (int)(~(unsigned)g);
    int js = __builtin_amdgcn_readfirstlane(j);      // uniform -> scalar loads
    const float* pc = base + 3 * js;
    cx = pc[0]; cy = pc[1]; cz = pc[2];              // bit-identical to source coords
    if (tid == 0) { float* o3 = sonew + 3 * it; o3[0] = cx; o3[1] = cy; o3[2] = cz; }
    cx2.x = cx; cx2.y = cx;
    cy2.x = cy; cy2.y = cy;
    cz2.x = cz; cz2.y = cz;
    // no second barrier: next iteration writes the OTHER parity's part[] cells
  }
  __syncthreads();
  // one coalesced copy of all 1024 centroids (3072 floats) to global
  float* onew = newxyz + (size_t)b * (NPT * 3);
  for (int i = tid; i < NPT * 3; i += 512) onew[i] = sonew[i];
}

// ------- Fused ball query (blocks 0..1023) + feature transpose (blocks 1024..2047) -------
// tr hides in BALL's dispatch, not fps's: ball is a throughput kernel (no serial chain to
// perturb), doesn't read featsT, and mlp launches only after this dispatch completes.
// LDS = 16.6KB tile + 0.5KB list = 17.2KB/block -> ball still wave-capped at 8 blocks/CU
// (no occupancy loss). Ball logic byte-identical to round-9 proven standalone kernel.
extern "C" __global__ __launch_bounds__(256)
void ball_kernel(const float* __restrict__ xyz, const float* __restrict__ newxyz,
                 int* __restrict__ ballidx,
                 const float* __restrict__ feats, float* __restrict__ featsT) {
  __shared__ int list[4][NS];
  __shared__ float t[64][65];           // transpose tile (+1 pad: conflict-free both phases)
  if (blockIdx.x >= NB * NPT / 4) {
    // ---------------- transpose role: (B,C,N) -> (B,N,C), 64x64 tile ----------------
    const int tt = blockIdx.x - NB * NPT / 4;
    const int tile = tt & 255, b = tt >> 8;
    const int j0 = tile * 64;
    const int lj = threadIdx.x & 63;    // lane = j (read) / cc (write)
    const int r0 = threadIdx.x >> 6;    // 0..3
    const float* fb = feats + (size_t)b * (CIN * NN);
#pragma unroll
    for (int cc = r0; cc < 64; cc += 4)
      t[cc][lj] = fb[(size_t)cc * NN + j0 + lj];      // coalesced along j
    __syncthreads();
    float* ob = featsT + (size_t)b * (NN * CIN);
#pragma unroll
    for (int jr = r0; jr < 64; jr += 4)
      ob[(size_t)(j0 + jr) * 64 + lj] = t[lj][jr];    // coalesced along cc
    return;
  }
  // ---------------- ball role: one wave per centroid, ordered append, early exit -------
  const int lwv = threadIdx.x >> 6, lane = threadIdx.x & 63;
  const int wid = blockIdx.x * 4 + lwv;  // centroid id, 0..4095
  const int b = wid >> 10;
  const float* base = xyz + (size_t)b * (NN * 3);
  const float* c = newxyz + (size_t)wid * 3;
  float cx = c[0], cy = c[1], cz = c[2];
  float c2 = __fadd_rn(__fadd_rn(__fmul_rn(cx, cx), __fmul_rn(cy, cy)), __fmul_rn(cz, cz));
  int cnt = 0;
  for (int j0 = 0; j0 < NN; j0 += 64) {
    int j = j0 + lane;
    float xx = base[3 * j + 0], xy = base[3 * j + 1], xz = base[3 * j + 2];
    float x2 = __fadd_rn(__fadd_rn(__fmul_rn(xx, xx), __fmul_rn(xy, xy)), __fmul_rn(xz, xz));
    float dt = __fadd_rn(__fadd_rn(__fmul_rn(cx, xx), __fmul_rn(cy, xy)), __fmul_rn(cz, xz));
    float d2 = __fsub_rn(__fadd_rn(c2, x2), __fmul_rn(2.0f, dt));  // (c2+x2) - 2*dot
    bool in = d2 < 0.25f;
    unsigned long long msk = __ballot(in);
    if (in) {
      int pos = cnt + (int)__popcll(msk & ((1ull << lane) - 1ull));
      if (pos < NS) list[lwv][pos] = j;
    }
    cnt += (int)__popcll(msk);
    if (cnt >= NS) break;
  }
  if (lane < NS) {
    int v;
    if (cnt == 0) v = 0;
    else v = (lane < cnt) ? list[lwv][lane] : list[lwv][0];
    ballidx[wid * NS + lane] = v;
  }
}

// ---------------- Gather + MLP(67->64->64->128) + max-pool, one block per (b,m) ----------------
extern "C" __global__ __launch_bounds__(256)
void mlp_kernel(const float* __restrict__ xyz, const float* __restrict__ feats,
                const float* __restrict__ featsT,   // point-major copy, or null (fallback)
                const float* __restrict__ newxyz, const int* __restrict__ ballidx,
                const float* __restrict__ W1, const float* __restrict__ b1,
                const float* __restrict__ W2, const float* __restrict__ b2,
                const float* __restrict__ W3, const float* __restrict__ b3,
                float* __restrict__ outf) {
  const int bm = blockIdx.x;
  const int b = bm >> 10, m = bm & 1023;
  const int tid = threadIdx.x;
  __align__(16) __shared__ float bufA[32 * 68];  // h0 (stride 68), then h2 (stride 64)
  __align__(16) __shared__ float bufB[32 * 64];  // h1, then partial max
  __shared__ int sidx[NS];
  if (tid < NS) sidx[tid] = ballidx[bm * NS + tid];
  const float* cb = newxyz + (size_t)bm * 3;
  float cx = cb[0], cy = cb[1], cz = cb[2];
  __syncthreads();
  // gather: 8 threads per sample
  {
    int s = tid >> 3, q = tid & 7;
    int j = sidx[s];
    float* row = bufA + s * 68;
    if (featsT) {
      const float* fr = featsT + ((size_t)b * NN + j) * 64 + (q << 3);
      float4 a0 = *(const float4*)fr;
      float4 a1 = *(const float4*)(fr + 4);
      float* rp = row + 3 + (q << 3);
      rp[0] = a0.x; rp[1] = a0.y; rp[2] = a0.z; rp[3] = a0.w;
      rp[4] = a1.x; rp[5] = a1.y; rp[6] = a1.z; rp[7] = a1.w;
    } else {
      const float* fb = feats + (size_t)b * (CIN * NN) + j;
#pragma unroll
      for (int u = 0; u < 8; ++u) {
        int cc = (q << 3) + u;
        row[3 + cc] = fb[(size_t)cc * NN];
      }
    }
    if (q == 0) {
      const float* p = xyz + ((size_t)b * NN + j) * 3;
      row[0] = __fsub_rn(p[0], cx);
      row[1] = __fsub_rn(p[1], cy);
      row[2] = __fsub_rn(p[2], cz);
      row[67] = 0.0f;
    }
  }
  __syncthreads();
  // layer 1: 67->64   (thread = (o, 8-sample group))
  {
    const int o = tid & 63, g = tid >> 6;
    float w[68];
    const float* wr = W1 + o * C0;
#pragma unroll
    for (int c = 0; c < C0; ++c) w[c] = wr[c];
    w[67] = 0.0f;
    float bias = b1[o];
    float acc[8];
#pragma unroll
    for (int k = 0; k < 8; ++k) acc[k] = bias;
#pragma unroll
    for (int c = 0; c < 68; c += 4) {
#pragma unroll
      for (int k = 0; k < 8; ++k) {
        float4 h = *(const float4*)(bufA + (g * 8 + k) * 68 + c);
        acc[k] = fmaf(w[c], h.x, acc[k]);
        acc[k] = fmaf(w[c + 1], h.y, acc[k]);
        acc[k] = fmaf(w[c + 2], h.z, acc[k]);
        acc[k] = fmaf(w[c + 3], h.w, acc[k]);
      }
    }
#pragma unroll
    for (int k = 0; k < 8; ++k) bufB[(g * 8 + k) * 64 + o] = fmaxf(acc[k], 0.0f);
  }
  __syncthreads();
  // layer 2: 64->64, h2 into bufA with stride 64
  {
    const int o = tid & 63, g = tid >> 6;
    float w[64];
    const float* wr = W2 + o * 64;
#pragma unroll
    for (int c = 0; c < 64; ++c) w[c] = wr[c];
    float bias = b2[o];
    float acc[8];
#pragma unroll
    for (int k = 0; k < 8; ++k) acc[k] = bias;
#pragma unroll
    for (int c = 0; c < 64; c += 4) {
#pragma unroll
      for (int k = 0; k < 8; ++k) {
        float4 h = *(const float4*)(bufB + (g * 8 + k) * 64 + c);
        acc[k] = fmaf(w[c], h.x, acc[k]);
        acc[k] = fmaf(w[c + 1], h.y, acc[k]);
        acc[k] = fmaf(w[c + 2], h.z, acc[k]);
        acc[k] = fmaf(w[c + 3], h.w, acc[k]);
      }
    }
#pragma unroll
    for (int k = 0; k < 8; ++k) bufA[(g * 8 + k) * 64 + o] = fmaxf(acc[k], 0.0f);
  }
  __syncthreads();
  // layer 3: 64->128 (thread = (o128, 16-sample group)), fused relu+max
  {
    const int o = tid & 127, g = tid >> 7;
    float w[64];
    const float* wr = W3 + o * 64;
#pragma unroll
    for (int c = 0; c < 64; ++c) w[c] = wr[c];
    float bias = b3[o];
    float acc[16];
#pragma unroll
    for (int k = 0; k < 16; ++k) acc[k] = bias;
#pragma unroll
    for (int kb = 0; kb < 16; kb += 8) {   // 8-sample sub-blocks to limit live registers
#pragma unroll
      for (int c = 0; c < 64; c += 4) {
#pragma unroll
        for (int k = 0; k < 8; ++k) {
          float4 h = *(const float4*)(bufA + (g * 16 + kb + k) * 64 + c);
          acc[kb + k] = fmaf(w[c], h.x, acc[kb + k]);
          acc[kb + k] = fmaf(w[c + 1], h.y, acc[kb + k]);
          acc[kb + k] = fmaf(w[c + 2], h.z, acc[kb + k]);
          acc[kb + k] = fmaf(w[c + 3], h.w, acc[kb + k]);
        }
      }
    }
    float mx = 0.0f;
#pragma unroll
    for (int k = 0; k < 16; ++k) mx = fmaxf(mx, fmaxf(acc[k], 0.0f));
    bufB[g * 128 + o] = mx;
  }
  __syncthreads();
  if (tid < 128) {
    float v = fmaxf(bufB[tid], bufB[128 + tid]);
    outf[((size_t)b * 128 + tid) * NPT + m] = v;
  }
}

extern "C" void kernel_launch(void* const* d_in, const int* in_sizes, int n_in,
                              void* d_out, int out_size, void* d_ws, size_t ws_size,
                              hipStream_t stream) {
  const float* xyz   = (const float*)d_in[0];
  const float* feats = (const float*)d_in[1];
  const float* W1 = (const float*)d_in[2];
  const float* b1 = (const float*)d_in[3];
  const float* W2 = (const float*)d_in[4];
  const float* b2 = (const float*)d_in[5];
  const float* W3 = (const float*)d_in[6];
  const float* b3 = (const float*)d_in[7];
  float* out = (float*)d_out;
  float* newxyz = out;                 // (4,1024,3)
  float* outf = out + NB * NPT * 3;    // (4,128,1024)
  int* ballidx = (int*)d_ws;           // 4096*32 ints at ws+0

  // featsT (16.78 MB) lives at ws+1MB if the workspace is big enough; else fall back
  const size_t ftOff = 1u << 20;
  const size_t ftBytes = (size_t)NB * NN * CIN * sizeof(float);
  float* featsT = (ws_size >= ftOff + ftBytes) ? (float*)((char*)d_ws + ftOff) : nullptr;

  hipLaunchKernelGGL(fps_kernel, dim3(NB), dim3(512), 0, stream, xyz, newxyz);
  // ball blocks 0..1023 + transpose blocks 1024..2047 in one dispatch (tr hides in ball)
  const int bgrid = featsT ? (NB * NPT / 4 + NB * (NN / 64)) : (NB * NPT / 4);
  hipLaunchKernelGGL(ball_kernel, dim3(bgrid), dim3(256), 0, stream,
                     xyz, newxyz, ballidx, feats, featsT);
  hipLaunchKernelGGL(mlp_kernel, dim3(NB * NPT), dim3(256), 0, stream,
                     xyz, feats, featsT, newxyz, ballidx, W1, b1, W2, b2, W3, b3, outf);
}

// Round 14
// 1778.597 us; speedup vs baseline: 1.0587x; 1.0085x over previous
//
#include <hip/hip_runtime.h>

#define NB 4
#define NN 16384
#define NPT 1024
#define NS 32
#define CIN 64
#define C0 67

typedef float v2f __attribute__((ext_vector_type(2)));

// DPP wave64 reduce ladders (VALU-only; HW-verified correct in rounds 3/5/6/9/10/11/12)
#define DPP_MAXF(r, ctrl)                                                                   \
  {                                                                                         \
    unsigned _m = (unsigned)__builtin_amdgcn_update_dpp(                                    \
        (int)__float_as_uint(r), (int)__float_as_uint(r), ctrl, 0xf, 0xf, false);           \
    r = fmaxf(r, __uint_as_float(_m));                                                      \
  }
#define DPP_MINU(r, ctrl)                                                                   \
  {                                                                                         \
    unsigned _m = (unsigned)__builtin_amdgcn_update_dpp((int)(r), (int)(r), ctrl, 0xf, 0xf, \
                                                        false);                             \
    r = (r < _m) ? r : _m;                                                                  \
  }

// ---------------- FPS: one block per batch, 512 threads, 32 pts/thread ----------------
// Round-12 proven standalone version (1532us), byte-identical. Round-13's extra sqn role
// dropped (low value, least-validated piece of the failed round). Keep pure.
extern "C" __global__ __attribute__((amdgpu_waves_per_eu(2, 2))) __launch_bounds__(512)
void fps_kernel(const float* __restrict__ xyz, float* __restrict__ newxyz) {
  const int b = blockIdx.x;
  const int tid = threadIdx.x;          // 0..511
  const int wv = tid >> 6, lane = tid & 63;
  const float* base = xyz + (size_t)b * (NN * 3);
  __shared__ unsigned long long part[2][8];  // parity-double-buffered wave-winner keys
  __shared__ float sonew[NPT * 3];           // centroid accumulator (12 KB)
  v2f x2[16], y2[16], z2[16], m2[16];
#pragma unroll
  for (int k = 0; k < 32; ++k) {
    int j = (k << 9) + tid;            // same global index mapping as rounds 0-12
    x2[k >> 1][k & 1] = base[3 * j + 0];
    y2[k >> 1][k & 1] = base[3 * j + 1];
    z2[k >> 1][k & 1] = base[3 * j + 2];
    m2[k >> 1][k & 1] = 1e10f;
  }
  // iteration 0: centroid = point 0 (broadcast load)
  float cx = base[0], cy = base[1], cz = base[2];
  if (tid == 0) { sonew[0] = cx; sonew[1] = cy; sonew[2] = cz; }
  v2f cx2 = {cx, cx}, cy2 = {cy, cy}, cz2 = {cz, cz};
  for (int it = 1; it < NPT; ++it) {
    const int p = it & 1;
    float bv = -1.0f;
    {
#pragma clang fp contract(off)
#pragma unroll
      for (int q = 0; q < 16; ++q) {
        v2f dx = x2[q] - cx2;          // exact IEEE sub per half
        v2f dy = y2[q] - cy2;
        v2f dz = z2[q] - cz2;
        v2f qx = dx * dx;              // no contraction (pragma)
        v2f qy = dy * dy;
        v2f qz = dz * dz;
        v2f ss = qx + qy;              // (dx2+dy2)
        v2f dd = ss + qz;              // +dz2   -- reference's exact order
        float a = fminf(m2[q].x, dd.x);
        float bmn = fminf(m2[q].y, dd.y);
        m2[q].x = a;
        m2[q].y = bmn;
        bv = fmaxf(bv, fmaxf(a, bmn)); // fuses to v_max3_f32
      }
    }
    // post-scan: smallest k with md[k]==bv (descending overwrite keeps smallest)
    int bk = 0;
#pragma unroll
    for (int k = 31; k >= 0; --k) {
      float v = (k & 1) ? m2[k >> 1].y : m2[k >> 1].x;
      bk = (v == bv) ? k : bk;
    }
    int bestj = (bk << 9) + tid;
    // phase A: wave max of bv via DPP ladder -> lane 63
    float r = bv;
    DPP_MAXF(r, 0x111); DPP_MAXF(r, 0x112); DPP_MAXF(r, 0x114);
    DPP_MAXF(r, 0x118); DPP_MAXF(r, 0x142); DPP_MAXF(r, 0x143);
    float wmax = __uint_as_float((unsigned)__builtin_amdgcn_readlane((int)__float_as_uint(r), 63));
    // phase B: min index among lanes holding the max (exact equality: min/max return operands)
    unsigned cj = (bv == wmax) ? (unsigned)bestj : 0x7FFFFFFFu;
    DPP_MINU(cj, 0x111); DPP_MINU(cj, 0x112); DPP_MINU(cj, 0x114);
    DPP_MINU(cj, 0x118); DPP_MINU(cj, 0x142); DPP_MINU(cj, 0x143);
    unsigned jw = (unsigned)__builtin_amdgcn_readlane((int)cj, 63);
    if (lane == 0)
      part[p][wv] = ((unsigned long long)__float_as_uint(wmax) << 32) | (unsigned)(~jw);
    __syncthreads();
    // every thread merges the 8 wave winners (broadcast LDS reads); ~j orders ties to min j
    unsigned long long g = part[p][0];
#pragma unroll
    for (int w = 1; w < 8; ++w) {
      unsigned long long o = part[p][w];
      g = (o > g) ? o : g;
    }
    int j = (int)(~(unsigned)g);
    int js = __builtin_amdgcn_readfirstlane(j);      // uniform -> scalar loads
    const float* pc = base + 3 * js;
    cx = pc[0]; cy = pc[1]; cz = pc[2];              // bit-identical to source coords
    if (tid == 0) { float* o3 = sonew + 3 * it; o3[0] = cx; o3[1] = cy; o3[2] = cz; }
    cx2.x = cx; cx2.y = cx;
    cy2.x = cy; cy2.y = cy;
    cz2.x = cz; cz2.y = cz;
    // no second barrier: next iteration writes the OTHER parity's part[] cells
  }
  __syncthreads();
  // one coalesced copy of all 1024 centroids (3072 floats) to global
  float* onew = newxyz + (size_t)b * (NPT * 3);
  for (int i = tid; i < NPT * 3; i += 512) onew[i] = sonew[i];
}

// ------- Fused ball query (blocks 0..1023) + feature transpose (blocks 1024..2047) -------
// Round-12 proven, byte-identical (x2q path dropped: ball early-exits, saving was ~5us).
extern "C" __global__ __launch_bounds__(256)
void ball_kernel(const float* __restrict__ xyz, const float* __restrict__ newxyz,
                 int* __restrict__ ballidx,
                 const float* __restrict__ feats, float* __restrict__ featsT) {
  __shared__ int list[4][NS];
  __shared__ float t[64][65];           // transpose tile (+1 pad: conflict-free both phases)
  if (blockIdx.x >= NB * NPT / 4) {
    // ---------------- transpose role: (B,C,N) -> (B,N,C), 64x64 tile ----------------
    const int tt = blockIdx.x - NB * NPT / 4;
    const int tile = tt & 255, b = tt >> 8;
    const int j0 = tile * 64;
    const int lj = threadIdx.x & 63;    // lane = j (read) / cc (write)
    const int r0 = threadIdx.x >> 6;    // 0..3
    const float* fb = feats + (size_t)b * (CIN * NN);
#pragma unroll
    for (int cc = r0; cc < 64; cc += 4)
      t[cc][lj] = fb[(size_t)cc * NN + j0 + lj];      // coalesced along j
    __syncthreads();
    float* ob = featsT + (size_t)b * (NN * CIN);
#pragma unroll
    for (int jr = r0; jr < 64; jr += 4)
      ob[(size_t)(j0 + jr) * 64 + lj] = t[lj][jr];    // coalesced along cc
    return;
  }
  // ---------------- ball role: one wave per centroid, ordered append, early exit -------
  const int lwv = threadIdx.x >> 6, lane = threadIdx.x & 63;
  const int wid = blockIdx.x * 4 + lwv;  // centroid id, 0..4095
  const int b = wid >> 10;
  const float* base = xyz + (size_t)b * (NN * 3);
  const float* c = newxyz + (size_t)wid * 3;
  float cx = c[0], cy = c[1], cz = c[2];
  float c2 = __fadd_rn(__fadd_rn(__fmul_rn(cx, cx), __fmul_rn(cy, cy)), __fmul_rn(cz, cz));
  int cnt = 0;
  for (int j0 = 0; j0 < NN; j0 += 64) {
    int j = j0 + lane;
    float xx = base[3 * j + 0], xy = base[3 * j + 1], xz = base[3 * j + 2];
    float x2 = __fadd_rn(__fadd_rn(__fmul_rn(xx, xx), __fmul_rn(xy, xy)), __fmul_rn(xz, xz));
    float dt = __fadd_rn(__fadd_rn(__fmul_rn(cx, xx), __fmul_rn(cy, xy)), __fmul_rn(cz, xz));
    float d2 = __fsub_rn(__fadd_rn(c2, x2), __fmul_rn(2.0f, dt));  // (c2+x2) - 2*dot
    bool in = d2 < 0.25f;
    unsigned long long msk = __ballot(in);
    if (in) {
      int pos = cnt + (int)__popcll(msk & ((1ull << lane) - 1ull));
      if (pos < NS) list[lwv][pos] = j;
    }
    cnt += (int)__popcll(msk);
    if (cnt >= NS) break;
  }
  if (lane < NS) {
    int v;
    if (cnt == 0) v = 0;
    else v = (lane < cnt) ? list[lwv][lane] : list[lwv][0];
    ballidx[wid * NS + lane] = v;
  }
}

// ---------------- Gather + MLP(67->64->64->128) + max-pool, one block per (b,m) ----------------
// THE single change this round: W1/W2 staged COALESCED into a 17.4KB LDS buffer
// (stride-68 rows, 16B-aligned). Rationale: per-o weight rows at 268B stride make every
// wave load touch 64 distinct L1 lines (TA-serialized line-gather, ~130 loads/wave vs
// 2080 FMAs); staging converts that to one coalesced pass + LDS reads. Same values, same
// FMA order => bit-exact. Cost: one extra barrier, LDS 17->34KB (5->4 blocks/CU).
// W3 (32KB) stays on the global path (layer-3 has 2x the FMA/load ratio).
extern "C" __global__ __launch_bounds__(256)
void mlp_kernel(const float* __restrict__ xyz, const float* __restrict__ feats,
                const float* __restrict__ featsT,   // point-major copy, or null (fallback)
                const float* __restrict__ newxyz, const int* __restrict__ ballidx,
                const float* __restrict__ W1, const float* __restrict__ b1,
                const float* __restrict__ W2, const float* __restrict__ b2,
                const float* __restrict__ W3, const float* __restrict__ b3,
                float* __restrict__ outf) {
  const int bm = blockIdx.x;
  const int b = bm >> 10, m = bm & 1023;
  const int tid = threadIdx.x;
  __align__(16) __shared__ float bufA[32 * 68];  // h0 (stride 68), then h2 (stride 64)
  __align__(16) __shared__ float bufB[32 * 64];  // h1, then partial max
  __align__(16) __shared__ float wbuf[64 * 68];  // staged W1, then W2 (stride 68)
  __shared__ int sidx[NS];
  if (tid < NS) sidx[tid] = ballidx[bm * NS + tid];
  const float* cb = newxyz + (size_t)bm * 3;
  float cx = cb[0], cy = cb[1], cz = cb[2];
  // stage W1 coalesced: 64 rows x 67 cols -> wbuf stride 68, col 67 zeroed
  for (int idx = tid; idx < 64 * C0; idx += 256) {
    int o = idx / C0, cc = idx - o * C0;
    wbuf[o * 68 + cc] = W1[idx];
  }
  if (tid < 64) wbuf[tid * 68 + 67] = 0.0f;
  __syncthreads();
  // gather: 8 threads per sample
  {
    int s = tid >> 3, q = tid & 7;
    int j = sidx[s];
    float* row = bufA + s * 68;
    if (featsT) {
      const float* fr = featsT + ((size_t)b * NN + j) * 64 + (q << 3);
      float4 a0 = *(const float4*)fr;
      float4 a1 = *(const float4*)(fr + 4);
      float* rp = row + 3 + (q << 3);
      rp[0] = a0.x; rp[1] = a0.y; rp[2] = a0.z; rp[3] = a0.w;
      rp[4] = a1.x; rp[5] = a1.y; rp[6] = a1.z; rp[7] = a1.w;
    } else {
      const float* fb = feats + (size_t)b * (CIN * NN) + j;
#pragma unroll
      for (int u = 0; u < 8; ++u) {
        int cc = (q << 3) + u;
        row[3 + cc] = fb[(size_t)cc * NN];
      }
    }
    if (q == 0) {
      const float* p = xyz + ((size_t)b * NN + j) * 3;
      row[0] = __fsub_rn(p[0], cx);
      row[1] = __fsub_rn(p[1], cy);
      row[2] = __fsub_rn(p[2], cz);
      row[67] = 0.0f;
    }
  }
  __syncthreads();
  // layer 1: 67->64   (thread = (o, 8-sample group)), weights from LDS
  {
    const int o = tid & 63, g = tid >> 6;
    float w[68];
    const float* wr = wbuf + o * 68;     // 272B rows, 16B-aligned
#pragma unroll
    for (int c = 0; c < 68; ++c) w[c] = wr[c];   // w[67] staged as 0
    float bias = b1[o];
    float acc[8];
#pragma unroll
    for (int k = 0; k < 8; ++k) acc[k] = bias;
#pragma unroll
    for (int c = 0; c < 68; c += 4) {
#pragma unroll
      for (int k = 0; k < 8; ++k) {
        float4 h = *(const float4*)(bufA + (g * 8 + k) * 68 + c);
        acc[k] = fmaf(w[c], h.x, acc[k]);
        acc[k] = fmaf(w[c + 1], h.y, acc[k]);
        acc[k] = fmaf(w[c + 2], h.z, acc[k]);
        acc[k] = fmaf(w[c + 3], h.w, acc[k]);
      }
    }
#pragma unroll
    for (int k = 0; k < 8; ++k) bufB[(g * 8 + k) * 64 + o] = fmaxf(acc[k], 0.0f);
  }
  __syncthreads();
  // stage W2 (overwrites wbuf; layer-1 reads are done)
  for (int idx = tid; idx < 64 * 64; idx += 256) {
    int o = idx >> 6, cc = idx & 63;
    wbuf[o * 68 + cc] = W2[idx];
  }
  __syncthreads();
  // layer 2: 64->64, h2 into bufA with stride 64, weights from LDS
  {
    const int o = tid & 63, g = tid >> 6;
    float w[64];
    const float* wr = wbuf + o * 68;
#pragma unroll
    for (int c = 0; c < 64; ++c) w[c] = wr[c];
    float bias = b2[o];
    float acc[8];
#pragma unroll
    for (int k = 0; k < 8; ++k) acc[k] = bias;
#pragma unroll
    for (int c = 0; c < 64; c += 4) {
#pragma unroll
      for (int k = 0; k < 8; ++k) {
        float4 h = *(const float4*)(bufB + (g * 8 + k) * 64 + c);
        acc[k] = fmaf(w[c], h.x, acc[k]);
        acc[k] = fmaf(w[c + 1], h.y, acc[k]);
        acc[k] = fmaf(w[c + 2], h.z, acc[k]);
        acc[k] = fmaf(w[c + 3], h.w, acc[k]);
      }
    }
#pragma unroll
    for (int k = 0; k < 8; ++k) bufA[(g * 8 + k) * 64 + o] = fmaxf(acc[k], 0.0f);
  }
  __syncthreads();
  // layer 3: 64->128 (thread = (o128, 16-sample group)), fused relu+max (weights global)
  {
    const int o = tid & 127, g = tid >> 7;
    float w[64];
    const float* wr = W3 + o * 64;
#pragma unroll
    for (int c = 0; c < 64; ++c) w[c] = wr[c];
    float bias = b3[o];
    float acc[16];
#pragma unroll
    for (int k = 0; k < 16; ++k) acc[k] = bias;
#pragma unroll
    for (int kb = 0; kb < 16; kb += 8) {   // 8-sample sub-blocks to limit live registers
#pragma unroll
      for (int c = 0; c < 64; c += 4) {
#pragma unroll
        for (int k = 0; k < 8; ++k) {
          float4 h = *(const float4*)(bufA + (g * 16 + kb + k) * 64 + c);
          acc[kb + k] = fmaf(w[c], h.x, acc[kb + k]);
          acc[kb + k] = fmaf(w[c + 1], h.y, acc[kb + k]);
          acc[kb + k] = fmaf(w[c + 2], h.z, acc[kb + k]);
          acc[kb + k] = fmaf(w[c + 3], h.w, acc[kb + k]);
        }
      }
    }
    float mx = 0.0f;
#pragma unroll
    for (int k = 0; k < 16; ++k) mx = fmaxf(mx, fmaxf(acc[k], 0.0f));
    bufB[g * 128 + o] = mx;
  }
  __syncthreads();
  if (tid < 128) {
    float v = fmaxf(bufB[tid], bufB[128 + tid]);
    outf[((size_t)b * 128 + tid) * NPT + m] = v;
  }
}

extern "C" void kernel_launch(void* const* d_in, const int* in_sizes, int n_in,
                              void* d_out, int out_size, void* d_ws, size_t ws_size,
                              hipStream_t stream) {
  const float* xyz   = (const float*)d_in[0];
  const float* feats = (const float*)d_in[1];
  const float* W1 = (const float*)d_in[2];
  const float* b1 = (const float*)d_in[3];
  const float* W2 = (const float*)d_in[4];
  const float* b2 = (const float*)d_in[5];
  const float* W3 = (const float*)d_in[6];
  const float* b3 = (const float*)d_in[7];
  float* out = (float*)d_out;
  float* newxyz = out;                 // (4,1024,3)
  float* outf = out + NB * NPT * 3;    // (4,128,1024)
  int* ballidx = (int*)d_ws;           // 4096*32 ints at ws+0

  // featsT (16.78 MB) lives at ws+1MB if the workspace is big enough; else fall back
  const size_t ftOff = 1u << 20;
  const size_t ftBytes = (size_t)NB * NN * CIN * sizeof(float);
  float* featsT = (ws_size >= ftOff + ftBytes) ? (float*)((char*)d_ws + ftOff) : nullptr;

  hipLaunchKernelGGL(fps_kernel, dim3(NB), dim3(512), 0, stream, xyz, newxyz);
  // ball blocks 0..1023 + transpose blocks 1024..2047 in one dispatch (tr hides in ball)
  const int bgrid = featsT ? (NB * NPT / 4 + NB * (NN / 64)) : (NB * NPT / 4);
  hipLaunchKernelGGL(ball_kernel, dim3(bgrid), dim3(256), 0, stream,
                     xyz, newxyz, ballidx, feats, featsT);
  hipLaunchKernelGGL(mlp_kernel, dim3(NB * NPT), dim3(256), 0, stream,
                     xyz, feats, featsT, newxyz, ballidx, W1, b1, W2, b2, W3, b3, outf);
}